// Round 9
// baseline (255.222 us; speedup 1.0000x reference)
//
#include <hip/hip_runtime.h>

typedef __attribute__((ext_vector_type(8))) short short8;    // bf16 frag
typedef __attribute__((ext_vector_type(8))) _Float16 half8;  // f16 frag
typedef __attribute__((ext_vector_type(4))) float f32x4;
typedef __attribute__((ext_vector_type(16))) float f32x16;
typedef __attribute__((ext_vector_type(4))) unsigned int u32x4;

#define MFMA_BF16(a, b, c) __builtin_amdgcn_mfma_f32_16x16x32_bf16(a, b, c, 0, 0, 0)
#define MFMA32_BF16(a, b, c) __builtin_amdgcn_mfma_f32_32x32x16_bf16(a, b, c, 0, 0, 0)
#define MFMA32_F16(a, b, c) __builtin_amdgcn_mfma_f32_32x32x16_f16(a, b, c, 0, 0, 0)

#define GLD16(g, l)                                                          \
  __builtin_amdgcn_global_load_lds(                                          \
      (const __attribute__((address_space(1))) unsigned int*)(g),            \
      (__attribute__((address_space(3))) unsigned int*)(l), 16, 0, 0)

__device__ __forceinline__ unsigned short f2bf(float f) {
  unsigned int u = __float_as_uint(f);
  u += 0x7fffu + ((u >> 16) & 1u);
  return (unsigned short)(u >> 16);
}

// ---------------- conversion kernels ----------------
__global__ __launch_bounds__(256) void cvt_f32_bf16_k(const float* __restrict__ in,
                                                      unsigned short* __restrict__ out,
                                                      int n4) {
  int i = blockIdx.x * 256 + threadIdx.x;
  if (i < n4) {
    float4 v = reinterpret_cast<const float4*>(in)[i];
    ushort4 o;
    o.x = f2bf(v.x); o.y = f2bf(v.y); o.z = f2bf(v.z); o.w = f2bf(v.w);
    reinterpret_cast<ushort4*>(out)[i] = o;
  }
}

// W [1024][N] fp32 -> Wt [N][1024] bf16, 64x64 LDS tile (coalesced both sides)
__global__ __launch_bounds__(256) void transpose_cvt_k(const float* __restrict__ W,
                                                       unsigned short* __restrict__ Wt,
                                                       int N) {
  __shared__ float tile[64][65];
  const int tid = threadIdx.x;
  const int tk = blockIdx.x * 64;
  const int tn = blockIdx.y * 64;
#pragma unroll
  for (int c = 0; c < 4; ++c) {
    int k = c * 16 + (tid >> 4);
    int n = (tid & 15) * 4;
    float4 v = *reinterpret_cast<const float4*>(&W[(size_t)(tk + k) * N + tn + n]);
    tile[k][n] = v.x; tile[k][n + 1] = v.y; tile[k][n + 2] = v.z; tile[k][n + 3] = v.w;
  }
  __syncthreads();
#pragma unroll
  for (int p = 0; p < 2; ++p) {
    int n = p * 32 + (tid >> 3);
    int k = (tid & 7) * 8;
    ushort4 a, b;
    a.x = f2bf(tile[k + 0][n]); a.y = f2bf(tile[k + 1][n]);
    a.z = f2bf(tile[k + 2][n]); a.w = f2bf(tile[k + 3][n]);
    b.x = f2bf(tile[k + 4][n]); b.y = f2bf(tile[k + 5][n]);
    b.z = f2bf(tile[k + 6][n]); b.w = f2bf(tile[k + 7][n]);
    *reinterpret_cast<ushort4*>(&Wt[(size_t)(tn + n) * 1024 + tk + k]) = a;
    *reinterpret_cast<ushort4*>(&Wt[(size_t)(tn + n) * 1024 + tk + k + 4]) = b;
  }
}

// ---------------- GEMM: C = A @ Bt^T + bias ----------------
// 128 x BN tile, BK=32, DOUBLE-BUFFERED staging with raw s_barrier + vmcnt(N):
// prefetch of tile kt+1 stays in flight across the barrier (AITER pattern).
template <int MODE, int BN>
__global__ __launch_bounds__(256, 4) void gemm_bt(const unsigned short* __restrict__ A,
                                                  const unsigned short* __restrict__ Bt,
                                                  const float* __restrict__ bias,
                                                  float* __restrict__ outF,
                                                  unsigned short* __restrict__ q_ws,
                                                  unsigned short* __restrict__ k_ws,
                                                  unsigned short* __restrict__ vt_ws,
                                                  int M, int N, int K) {
  constexpr int NJ = BN / 32;
  constexpr int NBG = BN / 64;  // B GLDs per thread per tile (A is 2)
  __shared__ unsigned short As[2][128 * 32];
  __shared__ unsigned short Bs[2][BN * 32];

  const int tid = threadIdx.x;
  const int wave = tid >> 6, lane = tid & 63;
  const int quad = lane >> 4, l15 = lane & 15;
  const int m0 = blockIdx.x * 128, n0 = blockIdx.y * BN;
  const int wm = (wave & 1) * 64, wn = (wave >> 1) * (BN / 2);

  const f32x4 zf = {0.f, 0.f, 0.f, 0.f};
  f32x4 acc[4][NJ];
#pragma unroll
  for (int i = 0; i < 4; ++i)
#pragma unroll
    for (int j = 0; j < NJ; ++j) acc[i][j] = zf;

  const int srow = tid >> 2;       // staging row 0..63 (+64 for 2nd A chunk)
  const int scol = (tid & 3) * 8;  // 16B chunk within the 32-col tile

  // prologue: stage tile 0 into buffer 0
#pragma unroll
  for (int g = 0; g < 2; ++g)
    GLD16(&A[(size_t)(m0 + g * 64 + srow) * K + scol], &As[0][g * 2048 + tid * 8]);
#pragma unroll
  for (int g = 0; g < NBG; ++g)
    GLD16(&Bt[(size_t)(n0 + g * 64 + srow) * K + scol], &Bs[0][g * 2048 + tid * 8]);

  const int nkt = K >> 5;
  for (int kt = 0; kt < nkt; ++kt) {
    const int cur = kt & 1, nxt = cur ^ 1;
    if (kt) asm volatile("s_barrier" ::: "memory");  // readers done with buf[nxt]
    const int pofs = ((kt + 1 < nkt) ? kt + 1 : kt) * 32;
#pragma unroll
    for (int g = 0; g < 2; ++g)
      GLD16(&A[(size_t)(m0 + g * 64 + srow) * K + pofs + scol], &As[nxt][g * 2048 + tid * 8]);
#pragma unroll
    for (int g = 0; g < NBG; ++g)
      GLD16(&Bt[(size_t)(n0 + g * 64 + srow) * K + pofs + scol], &Bs[nxt][g * 2048 + tid * 8]);
    // current tile staged (prev prefetch done); new prefetch stays in flight
    if (NBG == 2)
      asm volatile("s_waitcnt vmcnt(4)\n\ts_barrier" ::: "memory");
    else
      asm volatile("s_waitcnt vmcnt(3)\n\ts_barrier" ::: "memory");

    short8 af[4], bg[NJ];
#pragma unroll
    for (int i = 0; i < 4; ++i)
      af[i] = *reinterpret_cast<const short8*>(&As[cur][(wm + i * 16 + l15) * 32 + quad * 8]);
#pragma unroll
    for (int j = 0; j < NJ; ++j)
      bg[j] = *reinterpret_cast<const short8*>(&Bs[cur][(wn + j * 16 + l15) * 32 + quad * 8]);
#pragma unroll
    for (int i = 0; i < 4; ++i)
#pragma unroll
      for (int j = 0; j < NJ; ++j) acc[i][j] = MFMA_BF16(af[i], bg[j], acc[i][j]);
  }
  // drain prefetch: outstanding GLD at endpgm would corrupt successor's LDS
  asm volatile("s_waitcnt vmcnt(0)" ::: "memory");

  const float kScQ = 0.125f * 1.44269504088896f;  // log2(e)/sqrt(64)
  const int cls = n0 >> 10;
#pragma unroll
  for (int i = 0; i < 4; ++i) {
#pragma unroll
    for (int j = 0; j < NJ; ++j) {
      const int n = n0 + wn + j * 16 + l15;
      const float bv = bias[n];
      const int mb = m0 + wm + i * 16 + quad * 4;
      if (MODE == 1) {
#pragma unroll
        for (int r = 0; r < 4; ++r) outF[(size_t)(mb + r) * N + n] = acc[i][j][r] + bv;
      } else if (cls == 0) {
        const int b = mb >> 11, t0 = mb & 2047;
        const int h = n >> 6, d = n & 63;
#pragma unroll
        for (int r = 0; r < 4; ++r)
          q_ws[(((size_t)(b * 16 + h)) * 2048 + t0 + r) * 64 + d] =
              f2bf((acc[i][j][r] + bv) * kScQ);
      } else if (cls == 1) {
        const int b = mb >> 11, t0 = mb & 2047;
        const int n2 = n - 1024, h = n2 >> 6, d = n2 & 63;
#pragma unroll
        for (int r = 0; r < 4; ++r)
          k_ws[(((size_t)(b * 16 + h)) * 2048 + t0 + r) * 64 + d] = f2bf(acc[i][j][r] + bv);
      } else {
        const int b = mb >> 11, t0 = mb & 2047;
        const int n2 = n - 2048, h = n2 >> 6, d = n2 & 63;
        uint2 pk;
        pk.x = __builtin_bit_cast(unsigned int,
                                  __builtin_amdgcn_cvt_pkrtz(acc[i][j][0] + bv, acc[i][j][1] + bv));
        pk.y = __builtin_bit_cast(unsigned int,
                                  __builtin_amdgcn_cvt_pkrtz(acc[i][j][2] + bv, acc[i][j][3] + bv));
        *reinterpret_cast<uint2*>(
            &vt_ws[(((size_t)(b * 16 + h)) * 64 + d) * 2048 + t0]) = pk;
      }
    }
  }
}

// ---------------- flash attention: 32x32 MFMA, register P-transform ----------------
// Q,K: [B*H, T, 64] bf16 (Q pre-scaled, log2 domain); Vt: [B*H, 64, T] fp16.
// P goes C-layout -> PV B-operand entirely in registers via v_permlane32_swap_b32
// (col q's 32 values live in lanes L and L+32; one swap per packed pair).
__global__ __launch_bounds__(256, 4) void attn_k(const unsigned short* __restrict__ q_ws,
                                                 const unsigned short* __restrict__ k_ws,
                                                 const unsigned short* __restrict__ vt_ws,
                                                 unsigned short* __restrict__ att_ws) {
  const int T = 2048;
  const int bid = blockIdx.x;
  const int bh = (bid & 7) * 8 + ((bid >> 3) & 7);  // XCD-locality swizzle
  const int s = 15 - (bid >> 6);                    // heaviest strips first
  const int tid = threadIdx.x;
  const int wv = tid >> 6, lane = tid & 63;
  const int L = lane & 31, hl = lane >> 5;

  const unsigned short* Qh = q_ws + (size_t)bh * T * 64;
  const unsigned short* Kh = k_ws + (size_t)bh * T * 64;
  const _Float16* Vh = (const _Float16*)vt_ws + (size_t)bh * 64 * T;
  const int b = bh >> 4, h = bh & 15;

  __shared__ unsigned short Ks[2][64 * 64];  // dbuf, xor-swizzled 8-elem chunks
  __shared__ _Float16 Vs[2][64 * 64];

  const int qw = s * 4 + wv;     // 32-query tile index 0..63
  const int q0 = qw * 32;
  const int diagTile = qw >> 1;  // last 64-key tile this wave needs
  const int nk = 2 * s + 2;      // block-uniform trip count
  const int myq = q0 + L;

  // Q B-frags for 4 k-steps: B[n=q][k=kk*16+hl*8+j]
  short8 qb[4];
#pragma unroll
  for (int kk = 0; kk < 4; ++kk)
    qb[kk] = *reinterpret_cast<const short8*>(&Qh[(size_t)(q0 + L) * 64 + kk * 16 + hl * 8]);

  f32x16 o0 = {}, o1 = {};
  float l_i = 0.f;

  const int srow8 = tid >> 3;
  const int schunk = (tid & 7) ^ (srow8 & 7);

  GLD16(&Kh[(size_t)srow8 * 64 + schunk * 8], &Ks[0][tid * 8]);
  GLD16(&Kh[(size_t)(32 + srow8) * 64 + schunk * 8], &Ks[0][2048 + tid * 8]);
  GLD16(&Vh[(size_t)srow8 * T + schunk * 8], &Vs[0][tid * 8]);
  GLD16(&Vh[(size_t)(32 + srow8) * T + schunk * 8], &Vs[0][2048 + tid * 8]);

  for (int kt = 0; kt < nk; ++kt) {
    const int cur = kt & 1, nxt = cur ^ 1;
    if (kt) asm volatile("s_barrier" ::: "memory");  // all waves done with buf[nxt]
    const int pf = (kt + 1 < nk) ? kt + 1 : nk - 1;
    GLD16(&Kh[(size_t)(pf * 64 + srow8) * 64 + schunk * 8], &Ks[nxt][tid * 8]);
    GLD16(&Kh[(size_t)(pf * 64 + 32 + srow8) * 64 + schunk * 8], &Ks[nxt][2048 + tid * 8]);
    GLD16(&Vh[(size_t)srow8 * T + pf * 64 + schunk * 8], &Vs[nxt][tid * 8]);
    GLD16(&Vh[(size_t)(32 + srow8) * T + pf * 64 + schunk * 8], &Vs[nxt][2048 + tid * 8]);
    asm volatile("s_waitcnt vmcnt(4)\n\ts_barrier" ::: "memory");

    if (kt <= diagTile) {
      const unsigned short* KsC = Ks[cur];
      const _Float16* VsC = Vs[cur];
      const int kb = kt * 64;

      // S^T = K·Q^T, two 32-key tiles; C/D: col=lane&31, row=(r&3)+8(r>>2)+4hl
      f32x16 sc0 = {}, sc1 = {};
#pragma unroll
      for (int kk = 0; kk < 4; ++kk) {
        const int sl = ((kk * 2 + hl) ^ (L & 7)) * 8;
        short8 k0 = *reinterpret_cast<const short8*>(&KsC[L * 64 + sl]);
        short8 k1 = *reinterpret_cast<const short8*>(&KsC[(32 + L) * 64 + sl]);
        sc0 = MFMA32_BF16(k0, qb[kk], sc0);
        sc1 = MFMA32_BF16(k1, qb[kk], sc1);
      }
      if (kt == diagTile) {  // causal mask, diagonal tile only
#pragma unroll
        for (int reg = 0; reg < 16; ++reg) {
          const int row = (reg & 3) + 8 * (reg >> 2) + 4 * hl;
          sc0[reg] = (kb + row > myq) ? -1e30f : sc0[reg];
          sc1[reg] = (kb + 32 + row > myq) ? -1e30f : sc1[reg];
        }
      }
      // exp2 (log2-domain, fixed shift) + pack f16 pairs
      unsigned int qp[16];
#pragma unroll
      for (int c = 0; c < 2; ++c) {
        const f32x16& scc = c ? sc1 : sc0;
#pragma unroll
        for (int g = 0; g < 8; ++g) {
          float a0 = exp2f(scc[2 * g]);
          float a1 = exp2f(scc[2 * g + 1]);
          l_i += a0 + a1;
          qp[c * 8 + g] =
              __builtin_bit_cast(unsigned int, __builtin_amdgcn_cvt_pkrtz(a0, a1));
        }
      }
      // C-layout -> B-operand: swap D.hi with S.lo across half-waves
#pragma unroll
      for (int t = 0; t < 4; ++t) {
        asm volatile("v_permlane32_swap_b32 %0, %1"
                     : "+v"(qp[4 * t + 0]), "+v"(qp[4 * t + 2]));
        asm volatile("v_permlane32_swap_b32 %0, %1"
                     : "+v"(qp[4 * t + 1]), "+v"(qp[4 * t + 3]));
      }
      // O^T += V^T · P^T
#pragma unroll
      for (int t = 0; t < 4; ++t) {
        u32x4 bu = {qp[4 * t + 0], qp[4 * t + 1], qp[4 * t + 2], qp[4 * t + 3]};
        half8 pb = __builtin_bit_cast(half8, bu);
        const int sl = ((t * 2 + hl) ^ (L & 7)) * 8;
        half8 v0 = *reinterpret_cast<const half8*>(&VsC[L * 64 + sl]);
        half8 v1 = *reinterpret_cast<const half8*>(&VsC[(32 + L) * 64 + sl]);
        o0 = MFMA32_F16(v0, pb, o0);
        o1 = MFMA32_F16(v1, pb, o1);
      }
    }
  }
  asm volatile("s_waitcnt vmcnt(0)" ::: "memory");  // drain prefetch before exit

  l_i += __shfl_xor(l_i, 32);
  const float inv = 1.f / l_i;
#pragma unroll
  for (int sg = 0; sg < 2; ++sg) {
    const f32x16& oo = sg ? o1 : o0;
#pragma unroll
    for (int g = 0; g < 4; ++g) {
      const int d0 = sg * 32 + g * 8 + hl * 4;
      uint2 ov;
      ov.x = (unsigned)f2bf(oo[4 * g + 0] * inv) | ((unsigned)f2bf(oo[4 * g + 1] * inv) << 16);
      ov.y = (unsigned)f2bf(oo[4 * g + 2] * inv) | ((unsigned)f2bf(oo[4 * g + 3] * inv) << 16);
      *reinterpret_cast<uint2*>(
          &att_ws[(size_t)(b * 2048 + q0 + L) * 1024 + h * 64 + d0]) = ov;
    }
  }
}

// ---------------- launch ----------------
extern "C" void kernel_launch(void* const* d_in, const int* in_sizes, int n_in,
                              void* d_out, int out_size, void* d_ws, size_t ws_size,
                              hipStream_t stream) {
  (void)in_sizes; (void)n_in; (void)out_size; (void)ws_size;
  const float* x     = (const float*)d_in[0];
  const float* W_qkv = (const float*)d_in[1];
  const float* b_qkv = (const float*)d_in[2];
  const float* W_out = (const float*)d_in[3];
  const float* b_out = (const float*)d_in[4];
  float* out = (float*)d_out;

  char* ws = (char*)d_ws;
  unsigned short* xb    = (unsigned short*)(ws);
  unsigned short* wqkvT = (unsigned short*)(ws + 16777216);
  unsigned short* woutT = (unsigned short*)(ws + 23068672);
  unsigned short* q_ws  = (unsigned short*)(ws + 25165824);
  unsigned short* k_ws  = (unsigned short*)(ws + 41943040);
  unsigned short* vt_ws = (unsigned short*)(ws + 58720256);
  unsigned short* attb  = (unsigned short*)(ws + 75497472);

  cvt_f32_bf16_k<<<8192, 256, 0, stream>>>(x, xb, 2097152);
  transpose_cvt_k<<<dim3(16, 48), 256, 0, stream>>>(W_qkv, wqkvT, 3072);
  transpose_cvt_k<<<dim3(16, 16), 256, 0, stream>>>(W_out, woutT, 1024);

  dim3 g1(64, 24);
  gemm_bt<0, 128><<<g1, 256, 0, stream>>>(xb, wqkvT, b_qkv, nullptr, q_ws, k_ws, vt_ws,
                                          8192, 3072, 1024);
  attn_k<<<1024, 256, 0, stream>>>(q_ws, k_ws, vt_ws, attb);

  dim3 g2(64, 16);
  gemm_bt<1, 64><<<g2, 256, 0, stream>>>(attb, woutT, b_out, out, nullptr, nullptr, nullptr,
                                         8192, 1024, 1024);
}